// Round 11
// baseline (193.081 us; speedup 1.0000x reference)
//
#include <hip/hip_runtime.h>
#include <hip/hip_bf16.h>
#include <stdint.h>

#define HIDDEN 128
#define LDS_STRIDE 136   // shorts per col: 128 + 8 pad (bank-conflict-free ds_read_b128)

typedef __attribute__((ext_vector_type(8))) short short8;
typedef __attribute__((ext_vector_type(4))) unsigned uint4v;
typedef __attribute__((ext_vector_type(4))) float float4v;
typedef __attribute__((ext_vector_type(2))) float float2v;
typedef __attribute__((ext_vector_type(2))) unsigned uint2v;

static __device__ __forceinline__ unsigned short f2bf(float f) {
    union { float f; unsigned u; } v; v.f = f;
    unsigned r = (v.u + 0x7FFFu + ((v.u >> 16) & 1u)) >> 16;
    return (unsigned short)r;
}

// Fast pack f32->bf16 pair: round-half-up (+0x8000) then byte-perm. ±0.5 ULP like RNE.
static __device__ __forceinline__ unsigned pack2bf(float f0, float f1) {
    unsigned u0 = __float_as_uint(f0) + 0x8000u;
    unsigned u1 = __float_as_uint(f1) + 0x8000u;
    return __builtin_amdgcn_perm(u1, u0, 0x07060302u);
}

static __device__ __forceinline__ short8 pack8(float4v lo, float4v hi) {
    uint4v u;
    u[0] = pack2bf(lo[0], lo[1]);
    u[1] = pack2bf(lo[2], lo[3]);
    u[2] = pack2bf(hi[0], hi[1]);
    u[3] = pack2bf(hi[2], hi[3]);
    return *(short8*)&u;
}

// ---------------- prep + histogram ----------------
__global__ void prep_wt(const float* __restrict__ W1, const float* __restrict__ b1,
                        const float* __restrict__ W2,
                        unsigned short* __restrict__ Wt,
                        float* __restrict__ b1p, float* __restrict__ W2p,
                        const int* __restrict__ eli, int E, unsigned M,
                        int* __restrict__ cnt) {
    __shared__ int hh[64];
    int t = threadIdx.x;
    if (t < 64) hh[t] = 0;

    int idx = blockIdx.x * blockDim.x + t;             // 0 .. 32767
    if (idx < 256 * 128) {
        int j = idx >> 7, k = idx & 127;
        float v = (j < 128) ? W1[k * 128 + j] : W1[(128 + k) * 128 + (j - 128)];
        Wt[idx] = f2bf(v);
    }
    if (idx < 128) {
        int m = idx >> 3, tt = idx & 7;
        int jj = tt * 16 + m;
        b1p[idx] = b1[jj];
        W2p[idx] = W2[jj];
    }
    __syncthreads();
    for (int i = idx; i < E; i += gridDim.x * blockDim.x) {
        int r = eli[i], c = eli[E + i];
        int b = (int)(__umulhi((unsigned)r, M) * 8 + __umulhi((unsigned)c, M));
        atomicAdd(&hh[b], 1);
    }
    __syncthreads();
    if (t < 64 && hh[t] > 0) atomicAdd(&cnt[t], hh[t]);
}

// ---------------- bucket scan: one wave, shfl prefix sum ----------------
__global__ void bucket_scan(const int* __restrict__ cnt, int* __restrict__ boff,
                            int* __restrict__ cur) {
    int t = threadIdx.x;               // 64 threads = 1 wave
    int v = cnt[t];
    int s = v;
    #pragma unroll
    for (int d = 1; d < 64; d <<= 1) {
        int u = __shfl_up(s, d, 64);
        if (t >= d) s += u;
    }
    int excl = s - v;
    boff[t] = excl;
    cur[t]  = excl;
    if (t == 63) boff[64] = s;
}

// ---------------- scatter into 64 buckets (coalesced runs) ----------------
__global__ void edge_scatter(const int* __restrict__ eli, int E, unsigned M,
                             int* __restrict__ cur, int* __restrict__ sr,
                             unsigned long long* __restrict__ sce) {
    __shared__ int hh[64];
    __shared__ int base[64];
    const int CH = 4096;
    int t = threadIdx.x;
    int start = blockIdx.x * CH;
    if (start >= E) return;
    int end = min(start + CH, E);

    if (t < 64) hh[t] = 0;
    __syncthreads();
    for (int i = start + t; i < end; i += 256) {
        int r = eli[i], c = eli[E + i];
        int b = (int)(__umulhi((unsigned)r, M) * 8 + __umulhi((unsigned)c, M));
        atomicAdd(&hh[b], 1);
    }
    __syncthreads();
    if (t < 64) {
        base[t] = (hh[t] > 0) ? atomicAdd(&cur[t], hh[t]) : 0;
        hh[t] = 0;
    }
    __syncthreads();
    for (int i = start + t; i < end; i += 256) {
        int r = eli[i], c = eli[E + i];
        int b = (int)(__umulhi((unsigned)r, M) * 8 + __umulhi((unsigned)c, M));
        int p = base[b] + atomicAdd(&hh[b], 1);
        sr[p]  = r;
        sce[p] = ((unsigned long long)(unsigned)i << 32) | (unsigned)c;
    }
}

// ---------------- node GEMM: LDS-staged weights, int8 quantized output ----------------
__global__ __launch_bounds__(512) void node_gemm(
        const float* __restrict__ z, const unsigned short* __restrict__ Wt,
        const float* __restrict__ b1p,
        unsigned char* __restrict__ Qi, float* __restrict__ sA, float* __restrict__ sB,
        int n_nodes) {
    __shared__ unsigned short Wl[128 * LDS_STRIDE];   // 34816 B

    int tid  = threadIdx.x;
    int h    = blockIdx.x & 1;

    #pragma unroll
    for (int i = 0; i < 4; ++i) {
        int chunk = tid + i * 512;                 // 0..2047
        int c  = chunk >> 4;                       // local col 0..127
        int k0 = (chunk & 15) * 8;
        short8 v = *(const short8*)(Wt + h * 16384 + chunk * 8);
        *(short8*)(Wl + c * LDS_STRIDE + k0) = v;
    }
    __syncthreads();

    int lane = tid & 63;
    int wave = tid >> 6;                           // 0..7
    int m    = lane & 15;
    int quad = lane >> 4;

    float4v b1a = (float4v)(0.0f), b1b = (float4v)(0.0f);
    if (h == 0) {
        b1a = *(const float4v*)(b1p + m * 8);
        b1b = *(const float4v*)(b1p + m * 8 + 4);
    }
    float* sArr = (h == 0) ? sA : sB;

    int nTiles = (n_nodes + 15) >> 4;
    int tileStride = (gridDim.x >> 1) * 8;

    for (int tile = (blockIdx.x >> 1) * 8 + wave; tile < nTiles; tile += tileStride) {
        int nodebase = tile * 16;
        int row = nodebase + m;

        short8 a[4];
        {
            bool ok = row < n_nodes;
            const float* zp = z + (size_t)row * HIDDEN + quad * 8;
            #pragma unroll
            for (int s = 0; s < 4; ++s) {
                float4v z0 = ok ? *(const float4v*)(zp + s * 32)     : (float4v)(0.0f);
                float4v z1 = ok ? *(const float4v*)(zp + s * 32 + 4) : (float4v)(0.0f);
                a[s] = pack8(z0, z1);
            }
        }

        float4v acc[8];
        #pragma unroll
        for (int t = 0; t < 8; ++t) acc[t] = (float4v)(0.0f);

        #pragma unroll
        for (int t = 0; t < 8; ++t) {
            const unsigned short* wp = Wl + (t * 16 + m) * LDS_STRIDE + quad * 8;
            #pragma unroll
            for (int s = 0; s < 4; ++s) {
                short8 b = *(const short8*)(wp + s * 32);
                acc[t] = __builtin_amdgcn_mfma_f32_16x16x32_bf16(a[s], b, acc[t], 0, 0, 0);
            }
        }

        #pragma unroll
        for (int r = 0; r < 4; ++r) {
            int node = nodebase + quad * 4 + r;
            float v[8];
            v[0] = acc[0][r] + b1a[0]; v[1] = acc[1][r] + b1a[1];
            v[2] = acc[2][r] + b1a[2]; v[3] = acc[3][r] + b1a[3];
            v[4] = acc[4][r] + b1b[0]; v[5] = acc[5][r] + b1b[1];
            v[6] = acc[6][r] + b1b[2]; v[7] = acc[7][r] + b1b[3];

            float amax = fabsf(v[0]);
            #pragma unroll
            for (int t = 1; t < 8; ++t) amax = fmaxf(amax, fabsf(v[t]));
            amax = fmaxf(amax, __shfl_xor(amax, 1));
            amax = fmaxf(amax, __shfl_xor(amax, 2));
            amax = fmaxf(amax, __shfl_xor(amax, 4));
            amax = fmaxf(amax, __shfl_xor(amax, 8));
            amax = fmaxf(amax, 1e-30f);

            float inv = 126.5f * __builtin_amdgcn_rcpf(amax);
            float s   = amax * (1.0f / 126.5f);

            unsigned d0 = 0, d1 = 0;
            #pragma unroll
            for (int t = 0; t < 4; ++t) {
                int q = (int)rintf(fmaf(v[t], inv, 128.0f));
                d0 |= ((unsigned)q & 255u) << (8 * t);
            }
            #pragma unroll
            for (int t = 0; t < 4; ++t) {
                int q = (int)rintf(fmaf(v[4 + t], inv, 128.0f));
                d1 |= ((unsigned)q & 255u) << (8 * t);
            }

            if (node < n_nodes) {
                uint2v pk; pk[0] = d0; pk[1] = d1;
                *(uint2v*)(Qi + (size_t)node * 256 + h * 128 + m * 8) = pk;
                if (m == 0) sArr[node] = s;
            }
        }
    }
}

// ---------------- edge math: packed float2 dequant dot ----------------
static __device__ __forceinline__ float edge_dot8(uint2v u1, uint2v u2,
                                                  float a1, float a2,
                                                  const float2v* w2) {
    float offs = -128.0f * (a1 + a2);
    float2v off2; off2[0] = offs; off2[1] = offs;
    float2v a1v;  a1v[0] = a1;   a1v[1] = a1;
    float2v a2v;  a2v[0] = a2;   a2v[1] = a2;
    float2v acc2; acc2[0] = 0.0f; acc2[1] = 0.0f;
    #pragma unroll
    for (int d = 0; d < 2; ++d) {
        unsigned da = u1[d], db = u2[d];
        #pragma unroll
        for (int p = 0; p < 2; ++p) {
            float2v af, bf;
            af[0] = (float)((da >> (16 * p))     & 255u);
            af[1] = (float)((da >> (16 * p + 8)) & 255u);
            bf[0] = (float)((db >> (16 * p))     & 255u);
            bf[1] = (float)((db >> (16 * p + 8)) & 255u);
            float2v t = a2v * bf + off2;        // v_pk_fma_f32
            float2v s = a1v * af + t;           // v_pk_fma_f32
            s[0] = fmaxf(s[0], 0.0f);
            s[1] = fmaxf(s[1], 0.0f);           // v_pk_max_f32
            acc2 = acc2 + s * w2[2 * d + p];    // v_pk_fma_f32
        }
    }
    return acc2[0] + acc2[1];
}

struct Batch {
    uint2v u1[4], u2[4];
    float  s1[4], s2[4];
    int    oe[4];
    bool   ok[4];
};

static __device__ __forceinline__ void load_batch(
        int base, int g, int j0, int re,
        const int* __restrict__ sr, const unsigned long long* __restrict__ sce,
        const unsigned char* __restrict__ Qi,
        const float* __restrict__ sA, const float* __restrict__ sB, Batch& B) {
    #pragma unroll
    for (int i = 0; i < 4; ++i) {
        int e = base + i * 16 + g;
        bool ok = e < re;
        B.ok[i] = ok;
        int ee = ok ? e : (re - 1);
        int r = sr[ee];
        unsigned long long ce = sce[ee];
        int c = (int)(unsigned)(ce & 0xFFFFFFFFull);
        B.oe[i] = (int)(unsigned)(ce >> 32);
        B.u1[i] = *(const uint2v*)(Qi + (size_t)r * 256 + j0);
        B.u2[i] = *(const uint2v*)(Qi + (size_t)c * 256 + 128 + j0);
        B.s1[i] = sA[r];
        B.s2[i] = sB[c];
    }
}

// ---------------- bucketed edge kernel (XCD-pinned, 2-deep pipeline) ----------------
__global__ __launch_bounds__(256) void edge_kernel_b(
        const int* __restrict__ sr, const unsigned long long* __restrict__ sce,
        const int* __restrict__ boff,
        const unsigned char* __restrict__ Qi,
        const float* __restrict__ sA, const float* __restrict__ sB,
        const float* __restrict__ W2p, const float* __restrict__ b2,
        float* __restrict__ out) {
    int g      = threadIdx.x >> 4;
    int lane16 = threadIdx.x & 15;
    int j0 = lane16 * 8;

    float2v w2[4];
    #pragma unroll
    for (int k = 0; k < 4; ++k) w2[k] = ((const float2v*)(W2p + j0))[k];
    float bias2 = b2[0];

    int x  = blockIdx.x & 7;
    int kb = blockIdx.x >> 3;
    int K  = gridDim.x >> 3;
    int rs = boff[x * 8];
    int re = boff[x * 8 + 8];
    int stride = K * 64;
    int base = rs + kb * 64;
    if (base >= re) return;

    Batch cur, nxt;
    load_batch(base, g, j0, re, sr, sce, Qi, sA, sB, cur);

    while (base < re) {
        int nb = base + stride;
        bool has = nb < re;
        if (has) load_batch(nb, g, j0, re, sr, sce, Qi, sA, sB, nxt);

        #pragma unroll
        for (int i = 0; i < 4; ++i) {
            float acc = edge_dot8(cur.u1[i], cur.u2[i], cur.s1[i], cur.s2[i], w2);
            acc += __shfl_xor(acc, 1);
            acc += __shfl_xor(acc, 2);
            acc += __shfl_xor(acc, 4);
            acc += __shfl_xor(acc, 8);
            if (lane16 == 0 && cur.ok[i]) out[cur.oe[i]] = acc + bias2;
        }

        base = nb;
        if (has) cur = nxt;
    }
}

// Fallback (unsorted) if ws too small.
__global__ __launch_bounds__(256) void edge_kernel(
        const int* __restrict__ eli, const unsigned char* __restrict__ Qi,
        const float* __restrict__ sA, const float* __restrict__ sB,
        const float* __restrict__ W2p, const float* __restrict__ b2,
        float* __restrict__ out, int E) {
    int g      = threadIdx.x >> 4;
    int lane16 = threadIdx.x & 15;
    int j0 = lane16 * 8;

    float2v w2[4];
    #pragma unroll
    for (int k = 0; k < 4; ++k) w2[k] = ((const float2v*)(W2p + j0))[k];
    float bias2 = b2[0];

    int e0 = blockIdx.x * 64 + g;

    int idx_r[4], idx_c[4];
    #pragma unroll
    for (int i = 0; i < 4; ++i) {
        int e = e0 + i * 16;
        idx_r[i] = (e < E) ? eli[e]     : 0;
        idx_c[i] = (e < E) ? eli[E + e] : 0;
    }

    uint2v u1[4], u2[4];
    float s1[4], s2[4];
    #pragma unroll
    for (int i = 0; i < 4; ++i) {
        u1[i] = *(const uint2v*)(Qi + (size_t)idx_r[i] * 256 + j0);
        u2[i] = *(const uint2v*)(Qi + (size_t)idx_c[i] * 256 + 128 + j0);
        s1[i] = sA[idx_r[i]];
        s2[i] = sB[idx_c[i]];
    }

    #pragma unroll
    for (int i = 0; i < 4; ++i) {
        float acc = edge_dot8(u1[i], u2[i], s1[i], s2[i], w2);
        acc += __shfl_xor(acc, 1);
        acc += __shfl_xor(acc, 2);
        acc += __shfl_xor(acc, 4);
        acc += __shfl_xor(acc, 8);
        int e = e0 + i * 16;
        if (lane16 == 0 && e < E) out[e] = acc + bias2;
    }
}

extern "C" void kernel_launch(void* const* d_in, const int* in_sizes, int n_in,
                              void* d_out, int out_size, void* d_ws, size_t ws_size,
                              hipStream_t stream) {
    const float* z   = (const float*)d_in[0];
    const int*   eli = (const int*)d_in[1];
    const float* W1  = (const float*)d_in[2];
    const float* b1  = (const float*)d_in[3];
    const float* W2  = (const float*)d_in[4];
    const float* b2  = (const float*)d_in[5];
    int n_nodes = in_sizes[0] / HIDDEN;       // 100000
    int E       = in_sizes[1] / 2;            // 1000000
    float* out  = (float*)d_out;

    unsigned M = (unsigned)((((unsigned long long)8 << 32) + n_nodes - 1) / (unsigned)n_nodes);

    size_t off = 0;
    unsigned char* Qi  = (unsigned char*)d_ws;                 off += (size_t)n_nodes * 256;
    unsigned short* Wt = (unsigned short*)((char*)d_ws + off); off += 256 * 128 * 2;
    float* b1p = (float*)((char*)d_ws + off);                  off += 128 * 4;
    float* W2p = (float*)((char*)d_ws + off);                  off += 128 * 4;
    float* sA  = (float*)((char*)d_ws + off);                  off += (size_t)n_nodes * 4;
    float* sB  = (float*)((char*)d_ws + off);                  off += (size_t)n_nodes * 4;
    off = (off + 255) & ~(size_t)255;
    int* sr  = (int*)((char*)d_ws + off);                      off += (size_t)E * 4;
    off = (off + 7) & ~(size_t)7;
    unsigned long long* sce = (unsigned long long*)((char*)d_ws + off); off += (size_t)E * 8;
    int* cnt  = (int*)((char*)d_ws + off);                     off += 64 * 4;
    int* boff = (int*)((char*)d_ws + off);                     off += 65 * 4;
    int* cur  = (int*)((char*)d_ws + off);                     off += 64 * 4;
    bool use_sort = (off <= ws_size);

    if (use_sort) {
        hipMemsetAsync(cnt, 0, 64 * 4, stream);
        prep_wt<<<128, 256, 0, stream>>>(W1, b1, W2, Wt, b1p, W2p, eli, E, M, cnt);
        bucket_scan<<<1, 64, 0, stream>>>(cnt, boff, cur);
        edge_scatter<<<(E + 4095) / 4096, 256, 0, stream>>>(eli, E, M, cur, sr, sce);
        node_gemm<<<1024, 512, 0, stream>>>(z, Wt, b1p, Qi, sA, sB, n_nodes);
        edge_kernel_b<<<2048, 256, 0, stream>>>(sr, sce, boff, Qi, sA, sB, W2p, b2, out);
    } else {
        prep_wt<<<128, 256, 0, stream>>>(W1, b1, W2, Wt, b1p, W2p, eli, 0, M, (int*)Qi);
        node_gemm<<<1024, 512, 0, stream>>>(z, Wt, b1p, Qi, sA, sB, n_nodes);
        edge_kernel<<<(E + 63) / 64, 256, 0, stream>>>(eli, Qi, sA, sB, W2p, b2, out, E);
    }
}

// Round 12
// 159.884 us; speedup vs baseline: 1.2076x; 1.2076x over previous
//
#include <hip/hip_runtime.h>
#include <hip/hip_bf16.h>
#include <stdint.h>

#define HIDDEN 128
#define LDS_STRIDE 136   // shorts per col: 128 + 8 pad (2-way-max LDS banking on ds_read_b128)

typedef __attribute__((ext_vector_type(8))) short short8;
typedef __attribute__((ext_vector_type(4))) unsigned uint4v;
typedef __attribute__((ext_vector_type(4))) float float4v;
typedef __attribute__((ext_vector_type(2))) float float2v;
typedef __attribute__((ext_vector_type(2))) unsigned uint2v;

static __device__ __forceinline__ unsigned short f2bf(float f) {
    union { float f; unsigned u; } v; v.f = f;
    unsigned r = (v.u + 0x7FFFu + ((v.u >> 16) & 1u)) >> 16;
    return (unsigned short)r;
}

// Fast pack f32->bf16 pair: round-half-up (+0x8000) then byte-perm. ±0.5 ULP like RNE.
static __device__ __forceinline__ unsigned pack2bf(float f0, float f1) {
    unsigned u0 = __float_as_uint(f0) + 0x8000u;
    unsigned u1 = __float_as_uint(f1) + 0x8000u;
    return __builtin_amdgcn_perm(u1, u0, 0x07060302u);
}

static __device__ __forceinline__ short8 pack8(float4v lo, float4v hi) {
    uint4v u;
    u[0] = pack2bf(lo[0], lo[1]);
    u[1] = pack2bf(lo[2], lo[3]);
    u[2] = pack2bf(hi[0], hi[1]);
    u[3] = pack2bf(hi[2], hi[3]);
    return *(short8*)&u;
}

// ---------------- prep ----------------
// Wt[j*128+k] = combined W[k][j] (bf16). Permutation within each half:
// physical pp = m*8+tt  <->  logical jj = tt*16+m (b1/W2 permuted to match).
__global__ void prep_wt(const float* __restrict__ W1, const float* __restrict__ b1,
                        const float* __restrict__ W2,
                        unsigned short* __restrict__ Wt,
                        float* __restrict__ b1p, float* __restrict__ W2p) {
    int idx = blockIdx.x * blockDim.x + threadIdx.x;   // 0 .. 32767
    if (idx < 256 * 128) {
        int j = idx >> 7, k = idx & 127;
        float v = (j < 128) ? W1[k * 128 + j] : W1[(128 + k) * 128 + (j - 128)];
        Wt[idx] = f2bf(v);
    }
    if (idx < 128) {
        int m = idx >> 3, tt = idx & 7;
        int jj = tt * 16 + m;
        b1p[idx] = b1[jj];
        W2p[idx] = W2[jj];
    }
}

// ---------------- node GEMM: LDS-staged weights, int8 quantized output ----------------
// One 16-node tile per wave (1564 blocks x 8 waves covers 6250 tiles).
// z-loads issue BEFORE staging/sync so HBM latency hides behind the L2 staging.
// Qi[node][h*128+pp] = biased-uint8; dequant v = s*(q-128), s per (node,half) in sA/sB.
__global__ __launch_bounds__(512) void node_gemm(
        const float* __restrict__ z, const unsigned short* __restrict__ Wt,
        const float* __restrict__ b1p,
        unsigned char* __restrict__ Qi, float* __restrict__ sA, float* __restrict__ sB,
        int n_nodes) {
    __shared__ unsigned short Wl[128 * LDS_STRIDE];   // 34816 B

    int tid  = threadIdx.x;
    int h    = blockIdx.x & 1;
    int lane = tid & 63;
    int wave = tid >> 6;                           // 0..7
    int m    = lane & 15;
    int quad = lane >> 4;

    int nTiles   = (n_nodes + 15) >> 4;
    int tile     = (blockIdx.x >> 1) * 8 + wave;
    bool active  = tile < nTiles;
    int nodebase = tile * 16;
    int row      = nodebase + m;

    // ---- z loads first: independent of LDS, overlap with staging + sync ----
    float4v zr[8];
    {
        bool ok = active && (row < n_nodes);
        const float* zp = z + (size_t)row * HIDDEN + quad * 8;
        #pragma unroll
        for (int s = 0; s < 4; ++s) {
            zr[2 * s]     = ok ? *(const float4v*)(zp + s * 32)     : (float4v)(0.0f);
            zr[2 * s + 1] = ok ? *(const float4v*)(zp + s * 32 + 4) : (float4v)(0.0f);
        }
    }

    // ---- stage this half's weights into LDS (from L2-resident Wt) ----
    #pragma unroll
    for (int i = 0; i < 4; ++i) {
        int chunk = tid + i * 512;                 // 0..2047
        int c  = chunk >> 4;                       // local col 0..127
        int k0 = (chunk & 15) * 8;
        short8 v = *(const short8*)(Wt + h * 16384 + chunk * 8);
        *(short8*)(Wl + c * LDS_STRIDE + k0) = v;
    }
    __syncthreads();
    if (!active) return;

    float4v b1a = (float4v)(0.0f), b1b = (float4v)(0.0f);
    if (h == 0) {
        b1a = *(const float4v*)(b1p + m * 8);
        b1b = *(const float4v*)(b1p + m * 8 + 4);
    }
    float* sArr = (h == 0) ? sA : sB;

    short8 a[4];
    #pragma unroll
    for (int s = 0; s < 4; ++s) a[s] = pack8(zr[2 * s], zr[2 * s + 1]);

    float4v acc[8];
    #pragma unroll
    for (int t = 0; t < 8; ++t) acc[t] = (float4v)(0.0f);

    #pragma unroll
    for (int t = 0; t < 8; ++t) {
        const unsigned short* wp = Wl + (t * 16 + m) * LDS_STRIDE + quad * 8;
        #pragma unroll
        for (int s = 0; s < 4; ++s) {
            short8 b = *(const short8*)(wp + s * 32);
            acc[t] = __builtin_amdgcn_mfma_f32_16x16x32_bf16(a[s], b, acc[t], 0, 0, 0);
        }
    }

    // Epilogue: per node (quad,r): bias-fold, 16-lane row-max, int8 quantize.
    #pragma unroll
    for (int r = 0; r < 4; ++r) {
        int node = nodebase + quad * 4 + r;
        float v[8];
        v[0] = acc[0][r] + b1a[0]; v[1] = acc[1][r] + b1a[1];
        v[2] = acc[2][r] + b1a[2]; v[3] = acc[3][r] + b1a[3];
        v[4] = acc[4][r] + b1b[0]; v[5] = acc[5][r] + b1b[1];
        v[6] = acc[6][r] + b1b[2]; v[7] = acc[7][r] + b1b[3];

        float amax = fabsf(v[0]);
        #pragma unroll
        for (int t = 1; t < 8; ++t) amax = fmaxf(amax, fabsf(v[t]));
        amax = fmaxf(amax, __shfl_xor(amax, 1));
        amax = fmaxf(amax, __shfl_xor(amax, 2));
        amax = fmaxf(amax, __shfl_xor(amax, 4));
        amax = fmaxf(amax, __shfl_xor(amax, 8));
        amax = fmaxf(amax, 1e-30f);

        float inv = 126.5f * __builtin_amdgcn_rcpf(amax);
        float s   = amax * (1.0f / 126.5f);

        unsigned d0 = 0, d1 = 0;
        #pragma unroll
        for (int t = 0; t < 4; ++t) {
            int q = (int)rintf(fmaf(v[t], inv, 128.0f));
            d0 |= ((unsigned)q & 255u) << (8 * t);
        }
        #pragma unroll
        for (int t = 0; t < 4; ++t) {
            int q = (int)rintf(fmaf(v[4 + t], inv, 128.0f));
            d1 |= ((unsigned)q & 255u) << (8 * t);
        }

        if (node < n_nodes) {
            uint2v pk; pk[0] = d0; pk[1] = d1;
            *(uint2v*)(Qi + (size_t)node * 256 + h * 128 + m * 8) = pk;
            if (m == 0) sArr[node] = s;
        }
    }
}

// ---------------- edge math: packed float2 dequant dot ----------------
static __device__ __forceinline__ float edge_dot8(uint2v u1, uint2v u2,
                                                  float a1, float a2,
                                                  const float2v* w2) {
    float offs = -128.0f * (a1 + a2);
    float2v off2; off2[0] = offs; off2[1] = offs;
    float2v a1v;  a1v[0] = a1;   a1v[1] = a1;
    float2v a2v;  a2v[0] = a2;   a2v[1] = a2;
    float2v acc2; acc2[0] = 0.0f; acc2[1] = 0.0f;
    #pragma unroll
    for (int d = 0; d < 2; ++d) {
        unsigned da = u1[d], db = u2[d];
        #pragma unroll
        for (int p = 0; p < 2; ++p) {
            float2v af, bf;
            af[0] = (float)((da >> (16 * p))     & 255u);
            af[1] = (float)((da >> (16 * p + 8)) & 255u);
            bf[0] = (float)((db >> (16 * p))     & 255u);
            bf[1] = (float)((db >> (16 * p + 8)) & 255u);
            float2v t = a2v * bf + off2;        // v_pk_fma_f32
            float2v s = a1v * af + t;           // v_pk_fma_f32
            s[0] = fmaxf(s[0], 0.0f);
            s[1] = fmaxf(s[1], 0.0f);           // v_pk_max_f32
            acc2 = acc2 + s * w2[2 * d + p];    // v_pk_fma_f32
        }
    }
    return acc2[0] + acc2[1];
}

// ---------------- edge kernel (R9 plateau config, nontemporal out) ----------------
// out[e] = sum_pp relu(sA[r]*(a-128) + sB[c]*(b-128)) * W2p[pp] + b2  (b1 pre-folded)
__global__ __launch_bounds__(256) void edge_kernel(
        const int* __restrict__ eli, const unsigned char* __restrict__ Qi,
        const float* __restrict__ sA, const float* __restrict__ sB,
        const float* __restrict__ W2p, const float* __restrict__ b2,
        float* __restrict__ out, int E) {
    int g      = threadIdx.x >> 4;
    int lane16 = threadIdx.x & 15;
    int j0 = lane16 * 8;

    float2v w2[4];
    #pragma unroll
    for (int k = 0; k < 4; ++k) w2[k] = ((const float2v*)(W2p + j0))[k];
    float bias2 = b2[0];

    int e0 = blockIdx.x * 64 + g;

    int idx_r[4], idx_c[4];
    #pragma unroll
    for (int i = 0; i < 4; ++i) {
        int e = e0 + i * 16;
        idx_r[i] = (e < E) ? eli[e]     : 0;
        idx_c[i] = (e < E) ? eli[E + e] : 0;
    }

    uint2v u1[4], u2[4];
    float s1[4], s2[4];
    #pragma unroll
    for (int i = 0; i < 4; ++i) {
        u1[i] = *(const uint2v*)(Qi + (size_t)idx_r[i] * 256 + j0);
        u2[i] = *(const uint2v*)(Qi + (size_t)idx_c[i] * 256 + 128 + j0);
        s1[i] = sA[idx_r[i]];
        s2[i] = sB[idx_c[i]];
    }

    #pragma unroll
    for (int i = 0; i < 4; ++i) {
        float acc = edge_dot8(u1[i], u2[i], s1[i], s2[i], w2);
        acc += __shfl_xor(acc, 1);
        acc += __shfl_xor(acc, 2);
        acc += __shfl_xor(acc, 4);
        acc += __shfl_xor(acc, 8);
        int e = e0 + i * 16;
        if (lane16 == 0 && e < E)
            __builtin_nontemporal_store(acc + bias2, &out[e]);
    }
}

extern "C" void kernel_launch(void* const* d_in, const int* in_sizes, int n_in,
                              void* d_out, int out_size, void* d_ws, size_t ws_size,
                              hipStream_t stream) {
    const float* z   = (const float*)d_in[0];
    const int*   eli = (const int*)d_in[1];
    const float* W1  = (const float*)d_in[2];
    const float* b1  = (const float*)d_in[3];
    const float* W2  = (const float*)d_in[4];
    const float* b2  = (const float*)d_in[5];
    int n_nodes = in_sizes[0] / HIDDEN;       // 100000
    int E       = in_sizes[1] / 2;            // 1000000
    float* out  = (float*)d_out;

    size_t off = 0;
    unsigned char* Qi  = (unsigned char*)d_ws;                 off += (size_t)n_nodes * 256;
    unsigned short* Wt = (unsigned short*)((char*)d_ws + off); off += 256 * 128 * 2;
    float* b1p = (float*)((char*)d_ws + off);                  off += 128 * 4;
    float* W2p = (float*)((char*)d_ws + off);                  off += 128 * 4;
    float* sA  = (float*)((char*)d_ws + off);                  off += (size_t)n_nodes * 4;
    float* sB  = (float*)((char*)d_ws + off);                  off += (size_t)n_nodes * 4;

    prep_wt<<<128, 256, 0, stream>>>(W1, b1, W2, Wt, b1p, W2p);

    // 2 * ceil(6250/8) = 1564 blocks: each wave does exactly one 16-node tile.
    int nTiles = (n_nodes + 15) / 16;
    int blocksPerHalf = (nTiles + 7) / 8;
    node_gemm<<<2 * blocksPerHalf, 512, 0, stream>>>(z, Wt, b1p, Qi, sA, sB, n_nodes);

    edge_kernel<<<(E + 63) / 64, 256, 0, stream>>>(eli, Qi, sA, sB, W2p, b2, out, E);
}